// Round 2
// baseline (54347.698 us; speedup 1.0000x reference)
//
#include <hip/hip_runtime.h>
#include <cmath>
#include <vector>

#define B_SZ 64
#define SEQ 512
#define IN_D 512
#define HID 1024
#define MEM_DIM 8
#define ORD 256
#define MFLAT 2048
#define SDIM (HID + MFLAT)     // 3072 state (h|m)
#define KTOT (IN_D + SDIM)     // 3584
#define NCH (KTOT / 256)       // 14 chunks of 256

// ---------------- host-side expm (double, scaling & squaring) ----------------
static void matmul_d(const double* A, const double* B, double* C, int n) {
  for (int i = 0; i < n; ++i) {
    double* Ci = C + (size_t)i * n;
    for (int j = 0; j < n; ++j) Ci[j] = 0.0;
    const double* Ai = A + (size_t)i * n;
    for (int k = 0; k < n; ++k) {
      double a = Ai[k];
      const double* Bk = B + (size_t)k * n;
      for (int j = 0; j < n; ++j) Ci[j] += a * Bk[j];
    }
  }
}

// AdT[o*256+p] = Ad[p][o] (transposed), Anat[p*256+o] = Ad[p][o], Bd[p].
static void compute_AB_host(float* AdT, float* Anat, float* Bd) {
  const int q = ORD, n = ORD + 1;
  const double theta = 512.0;
  std::vector<double> M((size_t)n * n, 0.0);
  for (int i = 0; i < q; ++i) {
    double r = (2.0 * i + 1.0) / theta;
    for (int j = 0; j < q; ++j) {
      double v = (i < j) ? -1.0 : ((((i - j) % 2) == 1) ? 1.0 : -1.0);
      M[(size_t)i * n + j] = v * r;
    }
    M[(size_t)i * n + q] = (((i % 2) == 0) ? 1.0 : -1.0) * r;
  }
  double norm = 0.0;
  for (int j = 0; j < n; ++j) {
    double s = 0.0;
    for (int i = 0; i < n; ++i) s += fabs(M[(size_t)i * n + j]);
    if (s > norm) norm = s;
  }
  int s = 0;
  while (norm > 0.25) { norm *= 0.5; ++s; }
  double sc = ldexp(1.0, -s);
  for (size_t i = 0; i < M.size(); ++i) M[i] *= sc;
  std::vector<double> E((size_t)n * n, 0.0), P = M, T((size_t)n * n);
  for (int i = 0; i < n; ++i) E[(size_t)i * n + i] = 1.0;
  for (size_t i = 0; i < M.size(); ++i) E[i] += M[i];
  for (int k = 2; k <= 30; ++k) {
    matmul_d(P.data(), M.data(), T.data(), n);
    double inv = 1.0 / (double)k, mx = 0.0;
    for (size_t i = 0; i < T.size(); ++i) {
      T[i] *= inv;
      double a = fabs(T[i]);
      if (a > mx) mx = a;
    }
    P.swap(T);
    for (size_t i = 0; i < M.size(); ++i) E[i] += P[i];
    if (mx < 1e-19) break;
  }
  for (int it = 0; it < s; ++it) {
    matmul_d(E.data(), E.data(), T.data(), n);
    E.swap(T);
  }
  for (int p = 0; p < q; ++p) {
    for (int o = 0; o < q; ++o) {
      float v = (float)E[(size_t)p * n + o];
      AdT[(size_t)o * q + p] = v;
      Anat[(size_t)p * q + o] = v;
    }
    Bd[p] = (float)E[(size_t)p * n + q];
  }
}

// ---------------- precompute: WmB[i][d] = sum_p Wm[i][d*256+p] * Bd[p] ----------------
__global__ __launch_bounds__(256) void k_wmb(const float* __restrict__ Wm,
                                             const float* __restrict__ Bd,
                                             float* __restrict__ WmB) {
  int i = blockIdx.x;
  int d = threadIdx.x >> 5, l = threadIdx.x & 31;
  const float* wr = Wm + (size_t)i * MFLAT + d * ORD;
  float acc = 0.f;
  #pragma unroll
  for (int j = 0; j < 8; ++j) { int p = l + 32 * j; acc += wr[p] * Bd[p]; }
  for (int off = 16; off; off >>= 1) acc += __shfl_xor(acc, off);
  if (l == 0) WmB[i * 8 + d] = acc;
}

// ---------------- precompute: Gcat = [Gx | Gh' | Gm'] (1024 x 3584) ----------------
__global__ __launch_bounds__(256) void k_gcat(
    const float* __restrict__ Wx, const float* __restrict__ Wh,
    const float* __restrict__ Wm, const float* __restrict__ Ex,
    const float* __restrict__ Eh, const float* __restrict__ Em,
    const float* __restrict__ Anat, const float* __restrict__ WmB,
    float* __restrict__ Gcat) {
  __shared__ float wm[MFLAT];
  __shared__ float wb[8];
  int i = blockIdx.x, tid = threadIdx.x;
  for (int k = tid; k < MFLAT; k += 256) wm[k] = Wm[(size_t)i * MFLAT + k];
  if (tid < 8) wb[tid] = WmB[i * 8 + tid];
  __syncthreads();
  float* gr = Gcat + (size_t)i * KTOT;
  for (int c = tid; c < KTOT; c += 256) {
    float v;
    if (c < IN_D) {
      v = Wx[(size_t)i * IN_D + c];
      #pragma unroll
      for (int d = 0; d < 8; ++d) v += wb[d] * Ex[(size_t)d * IN_D + c];
    } else if (c < IN_D + HID) {
      int j = c - IN_D;
      v = Wh[(size_t)i * HID + j];
      #pragma unroll
      for (int d = 0; d < 8; ++d) v += wb[d] * Eh[(size_t)d * HID + j];
    } else {
      int cm = c - IN_D - HID;        // (d,o)
      int dd = cm >> 8, o = cm & 255;
      v = 0.f;
      const float* wmd = wm + dd * ORD;
      for (int p = 0; p < ORD; ++p) v += wmd[p] * Anat[(size_t)p * ORD + o];
      #pragma unroll
      for (int d = 0; d < 8; ++d) v += wb[d] * Em[(size_t)d * MFLAT + cm];
    }
    gr[c] = v;
  }
}

// ---------------- per-step fused kernel ----------------
// blocks 0..63: M role (one per batch b): u-dot + A-matvec -> m'
// blocks 64..319: H role: 16b x 16i tile of h' = tanh(Gcat . [x;h;m])
__global__ __launch_bounds__(256) void k_step(
    const float* __restrict__ x, const float* __restrict__ Ex,
    const float* __restrict__ Eh, const float* __restrict__ Em,
    const float* __restrict__ Gcat, const float* __restrict__ AdT,
    const float* __restrict__ Bd,
    const float* __restrict__ scur, float* __restrict__ snxt,
    float* __restrict__ out, int t) {
  __shared__ float sm[16384];   // 64 KiB, role-shared
  __shared__ float ush[8];
  int tid = threadIdx.x;

  if (blockIdx.x < 64) {
    // ================= M role =================
    int b = blockIdx.x;
    const float4* src4 = (const float4*)(scur + (size_t)b * SDIM);
    float4* sm4 = (float4*)sm;
    for (int g = tid; g < SDIM / 4; g += 256) sm4[g] = src4[g];
    __syncthreads();
    // u[d] = Ex.x + Eh.h + Em.m   (32 lanes per d)
    int d = tid >> 5, l = tid & 31;
    const float* xrow = x + ((size_t)b * SEQ + t) * IN_D;
    float acc = 0.f;
    for (int it = 0; it < 16; ++it) { int k = l + 32 * it; acc += Ex[(size_t)d * IN_D + k] * xrow[k]; }
    for (int it = 0; it < 32; ++it) { int k = l + 32 * it; acc += Eh[(size_t)d * HID + k] * sm[k]; }
    for (int it = 0; it < 64; ++it) { int k = l + 32 * it; acc += Em[(size_t)d * MFLAT + k] * sm[HID + k]; }
    for (int off = 16; off; off >>= 1) acc += __shfl_xor(acc, off);
    if (l == 0) ush[d] = acc;
    __syncthreads();
    // m'[d][p] = sum_o A[p][o] m[d][o] + Bd[p]*u[d];  thread -> (d, p0 = l*8)
    int p0 = l * 8;
    float u = ush[d];
    const float4* bd4 = (const float4*)(Bd + p0);
    float4 b0q = bd4[0], b1q = bd4[1];
    float a0 = b0q.x * u, a1 = b0q.y * u, a2 = b0q.z * u, a3 = b0q.w * u;
    float a4 = b1q.x * u, a5 = b1q.y * u, a6 = b1q.z * u, a7 = b1q.w * u;
    const float* mrow = sm + HID + d * ORD;
    for (int o = 0; o < ORD; ++o) {
      float mv = mrow[o];
      const float4* aq = (const float4*)(AdT + (size_t)o * ORD + p0);
      float4 q0 = aq[0], q1 = aq[1];
      a0 = fmaf(q0.x, mv, a0); a1 = fmaf(q0.y, mv, a1);
      a2 = fmaf(q0.z, mv, a2); a3 = fmaf(q0.w, mv, a3);
      a4 = fmaf(q1.x, mv, a4); a5 = fmaf(q1.y, mv, a5);
      a6 = fmaf(q1.z, mv, a6); a7 = fmaf(q1.w, mv, a7);
    }
    float4* mo4 = (float4*)(snxt + (size_t)b * SDIM + HID + d * ORD + p0);
    mo4[0] = make_float4(a0, a1, a2, a3);
    mo4[1] = make_float4(a4, a5, a6, a7);
  } else {
    // ================= H role =================
    int hid_ = blockIdx.x - 64;
    int bt = hid_ >> 6, itl = hid_ & 63;
    int b0 = bt * 16, i0 = itl * 16;
    int w = tid >> 6, lane = tid & 63;
    int pos_b = w >> 1, pos_i = w & 1;
    float acc[64];
    #pragma unroll
    for (int j = 0; j < 64; ++j) acc[j] = 0.f;

    for (int c = 0; c < NCH; ++c) {
      __syncthreads();
      int k0 = c * 256;
      // stage 32 rows x 256 k: slot = r*256 + tid; row = r*4+w; col-quad = lane
      #pragma unroll
      for (int r = 0; r < 8; ++r) {
        int row = r * 4 + w;     // 0..31
        const float4* g4;
        if (row < 16) {
          int bb = b0 + row;
          if (k0 < IN_D) g4 = (const float4*)(x + ((size_t)bb * SEQ + t) * IN_D + k0) + lane;
          else           g4 = (const float4*)(scur + (size_t)bb * SDIM + (k0 - IN_D)) + lane;
        } else {
          int ii = i0 + row - 16;
          g4 = (const float4*)(Gcat + (size_t)ii * KTOT + k0) + lane;
        }
        ((float4*)sm)[r * 256 + tid] = *g4;
      }
      __syncthreads();
      // compute: thread's k-quad = lane
      const float4* sb = (const float4*)sm;
      float4 sf[8], gf[8];
      #pragma unroll
      for (int j = 0; j < 8; ++j) {
        sf[j] = sb[(pos_b * 8 + j) * 64 + lane];
        gf[j] = sb[(16 + pos_i * 8 + j) * 64 + lane];
      }
      #pragma unroll
      for (int mb = 0; mb < 8; ++mb) {
        #pragma unroll
        for (int mi = 0; mi < 8; ++mi) {
          acc[mb * 8 + mi] += sf[mb].x * gf[mi].x + sf[mb].y * gf[mi].y
                            + sf[mb].z * gf[mi].z + sf[mb].w * gf[mi].w;
        }
      }
    }
    // reduce 64 k-slots: red[s=lane][p=w][j] at float idx s*256 + p*64 + j
    __syncthreads();
    {
      float4* red4 = (float4*)sm;
      #pragma unroll
      for (int j4 = 0; j4 < 16; ++j4) {
        int j = j4 * 4;
        red4[(lane * 4 + w) * 16 + j4] = make_float4(acc[j], acc[j + 1], acc[j + 2], acc[j + 3]);
      }
    }
    __syncthreads();
    int bl = tid >> 4, il = tid & 15;
    int p = ((bl >> 3) << 1) | (il >> 3);
    int j = (bl & 7) * 8 + (il & 7);
    float v = 0.f;
    for (int s = 0; s < 64; ++s) v += sm[s * 256 + p * 64 + j];
    float hv = tanhf(v);
    int bb = b0 + bl, ii = i0 + il;
    snxt[(size_t)bb * SDIM + ii] = hv;
    out[((size_t)bb * SEQ + t) * HID + ii] = hv;
  }
}

// ---------------- launch ----------------
extern "C" void kernel_launch(void* const* d_in, const int* in_sizes, int n_in,
                              void* d_out, int out_size, void* d_ws, size_t ws_size,
                              hipStream_t stream) {
  const float* x  = (const float*)d_in[0];
  const float* Ex = (const float*)d_in[1];
  const float* Eh = (const float*)d_in[2];
  const float* Em = (const float*)d_in[3];
  const float* Wx = (const float*)d_in[4];
  const float* Wh = (const float*)d_in[5];
  const float* Wm = (const float*)d_in[6];
  float* out = (float*)d_out;
  float* ws = (float*)d_ws;

  // ws layout (floats):
  float* dAnat = ws;                       // 65536
  float* dAdT  = dAnat + 65536;            // 65536
  float* dBd   = dAdT + 65536;             // 256 (+256 pad)
  float* dWmB  = dBd + 512;                // 8192
  float* dGcat = dWmB + 8192;              // 1024*3584 = 3,670,016
  float* scat0 = dGcat + (size_t)HID * KTOT;
  float* scat1 = scat0 + (size_t)B_SZ * SDIM;
  float* sc[2] = { scat0, scat1 };

  static float h_AdT[ORD * ORD];
  static float h_Anat[ORD * ORD];
  static float h_Bd[ORD];
  compute_AB_host(h_AdT, h_Anat, h_Bd);
  hipMemcpyAsync(dAdT,  h_AdT,  sizeof(h_AdT),  hipMemcpyHostToDevice, stream);
  hipMemcpyAsync(dAnat, h_Anat, sizeof(h_Anat), hipMemcpyHostToDevice, stream);
  hipMemcpyAsync(dBd,   h_Bd,   sizeof(h_Bd),   hipMemcpyHostToDevice, stream);

  hipMemsetAsync(sc[0], 0, (size_t)B_SZ * SDIM * sizeof(float), stream);

  k_wmb<<<dim3(HID), dim3(256), 0, stream>>>(Wm, dBd, dWmB);
  k_gcat<<<dim3(HID), dim3(256), 0, stream>>>(Wx, Wh, Wm, Ex, Eh, Em, dAnat, dWmB, dGcat);

  for (int t = 0; t < SEQ; ++t) {
    int cur = t & 1, nxt = cur ^ 1;
    k_step<<<dim3(320), dim3(256), 0, stream>>>(
        x, Ex, Eh, Em, dGcat, dAdT, dBd, sc[cur], sc[nxt], out, t);
  }
}

// Round 3
// 29277.142 us; speedup vs baseline: 1.8563x; 1.8563x over previous
//
#include <hip/hip_runtime.h>
#include <cmath>
#include <vector>

#define B_SZ 64
#define SEQ 512
#define IN_D 512
#define HID 1024
#define MEM_DIM 8
#define ORD 256
#define MFLAT 2048
#define SDIM (HID + MFLAT)     // 3072 state (h|m)
#define KTOT (IN_D + SDIM)     // 3584
#define NCH (KTOT / 256)       // 14 chunks of 256
#define NBLK 320

// ---------------- host-side expm (double, scaling & squaring) ----------------
static void matmul_d(const double* A, const double* B, double* C, int n) {
  for (int i = 0; i < n; ++i) {
    double* Ci = C + (size_t)i * n;
    for (int j = 0; j < n; ++j) Ci[j] = 0.0;
    const double* Ai = A + (size_t)i * n;
    for (int k = 0; k < n; ++k) {
      double a = Ai[k];
      const double* Bk = B + (size_t)k * n;
      for (int j = 0; j < n; ++j) Ci[j] += a * Bk[j];
    }
  }
}

static void compute_AB_host(float* AdT, float* Anat, float* Bd) {
  const int q = ORD, n = ORD + 1;
  const double theta = 512.0;
  std::vector<double> M((size_t)n * n, 0.0);
  for (int i = 0; i < q; ++i) {
    double r = (2.0 * i + 1.0) / theta;
    for (int j = 0; j < q; ++j) {
      double v = (i < j) ? -1.0 : ((((i - j) % 2) == 1) ? 1.0 : -1.0);
      M[(size_t)i * n + j] = v * r;
    }
    M[(size_t)i * n + q] = (((i % 2) == 0) ? 1.0 : -1.0) * r;
  }
  double norm = 0.0;
  for (int j = 0; j < n; ++j) {
    double s = 0.0;
    for (int i = 0; i < n; ++i) s += fabs(M[(size_t)i * n + j]);
    if (s > norm) norm = s;
  }
  int s = 0;
  while (norm > 0.25) { norm *= 0.5; ++s; }
  double sc = ldexp(1.0, -s);
  for (size_t i = 0; i < M.size(); ++i) M[i] *= sc;
  std::vector<double> E((size_t)n * n, 0.0), P = M, T((size_t)n * n);
  for (int i = 0; i < n; ++i) E[(size_t)i * n + i] = 1.0;
  for (size_t i = 0; i < M.size(); ++i) E[i] += M[i];
  for (int k = 2; k <= 30; ++k) {
    matmul_d(P.data(), M.data(), T.data(), n);
    double inv = 1.0 / (double)k, mx = 0.0;
    for (size_t i = 0; i < T.size(); ++i) {
      T[i] *= inv;
      double a = fabs(T[i]);
      if (a > mx) mx = a;
    }
    P.swap(T);
    for (size_t i = 0; i < M.size(); ++i) E[i] += P[i];
    if (mx < 1e-19) break;
  }
  for (int it = 0; it < s; ++it) {
    matmul_d(E.data(), E.data(), T.data(), n);
    E.swap(T);
  }
  for (int p = 0; p < q; ++p) {
    for (int o = 0; o < q; ++o) {
      float v = (float)E[(size_t)p * n + o];
      AdT[(size_t)o * q + p] = v;
      Anat[(size_t)p * q + o] = v;
    }
    Bd[p] = (float)E[(size_t)p * n + q];
  }
}

// ---------------- precompute: WmB[i][d] = sum_p Wm[i][d*256+p] * Bd[p] ----------------
__global__ __launch_bounds__(256) void k_wmb(const float* __restrict__ Wm,
                                             const float* __restrict__ Bd,
                                             float* __restrict__ WmB) {
  int i = blockIdx.x;
  int d = threadIdx.x >> 5, l = threadIdx.x & 31;
  const float* wr = Wm + (size_t)i * MFLAT + d * ORD;
  float acc = 0.f;
  #pragma unroll
  for (int j = 0; j < 8; ++j) { int p = l + 32 * j; acc += wr[p] * Bd[p]; }
  for (int off = 16; off; off >>= 1) acc += __shfl_xor(acc, off);
  if (l == 0) WmB[i * 8 + d] = acc;
}

// ---------------- precompute: Gcat = [Gx | Gh' | Gm'] (1024 x 3584) ----------------
__global__ __launch_bounds__(256) void k_gcat(
    const float* __restrict__ Wx, const float* __restrict__ Wh,
    const float* __restrict__ Wm, const float* __restrict__ Ex,
    const float* __restrict__ Eh, const float* __restrict__ Em,
    const float* __restrict__ Anat, const float* __restrict__ WmB,
    float* __restrict__ Gcat) {
  __shared__ float wm[MFLAT];
  __shared__ float wb[8];
  int i = blockIdx.x, tid = threadIdx.x;
  for (int k = tid; k < MFLAT; k += 256) wm[k] = Wm[(size_t)i * MFLAT + k];
  if (tid < 8) wb[tid] = WmB[i * 8 + tid];
  __syncthreads();
  float* gr = Gcat + (size_t)i * KTOT;
  for (int c = tid; c < KTOT; c += 256) {
    float v;
    if (c < IN_D) {
      v = Wx[(size_t)i * IN_D + c];
      #pragma unroll
      for (int d = 0; d < 8; ++d) v += wb[d] * Ex[(size_t)d * IN_D + c];
    } else if (c < IN_D + HID) {
      int j = c - IN_D;
      v = Wh[(size_t)i * HID + j];
      #pragma unroll
      for (int d = 0; d < 8; ++d) v += wb[d] * Eh[(size_t)d * HID + j];
    } else {
      int cm = c - IN_D - HID;        // (d,o)
      int dd = cm >> 8, o = cm & 255;
      v = 0.f;
      const float* wmd = wm + dd * ORD;
      for (int p = 0; p < ORD; ++p) v += wmd[p] * Anat[(size_t)p * ORD + o];
      #pragma unroll
      for (int d = 0; d < 8; ++d) v += wb[d] * Em[(size_t)d * MFLAT + cm];
    }
    gr[c] = v;
  }
}

// ---------------- device-scope grid barrier ----------------
__device__ inline void grid_barrier(unsigned* cnt, unsigned target) {
  __syncthreads();                       // all waves' stores drained (vmcnt(0) before s_barrier)
  if (threadIdx.x == 0) {
    __hip_atomic_fetch_add(cnt, 1u, __ATOMIC_RELEASE, __HIP_MEMORY_SCOPE_AGENT);
    while (__hip_atomic_load(cnt, __ATOMIC_RELAXED, __HIP_MEMORY_SCOPE_AGENT) < target)
      __builtin_amdgcn_s_sleep(2);
    __builtin_amdgcn_fence(__ATOMIC_ACQUIRE, "agent");   // invalidate stale L1/L2
  }
  __syncthreads();
}

// ---------------- persistent kernel: all 512 steps ----------------
// blocks 0..63: M role (one per batch b). blocks 64..319: H role (16b x 16i tile).
__global__ __launch_bounds__(256, 2) void k_persist(
    const float* __restrict__ x, const float* __restrict__ Ex,
    const float* __restrict__ Eh, const float* __restrict__ Em,
    const float* __restrict__ Gcat, const float* __restrict__ AdT,
    const float* __restrict__ Bd,
    float* __restrict__ s0, float* __restrict__ s1,
    float* __restrict__ out, unsigned* __restrict__ cnt) {
  __shared__ float sm[16384];   // 64 KiB, role-shared
  __shared__ float ush[8];
  int tid = threadIdx.x;

  if (blockIdx.x < 64) {
    // ================= M role =================
    int b = blockIdx.x;
    for (int t = 0; t < SEQ; ++t) {
      const float* scur = (t & 1) ? s1 : s0;
      float* snxt = (t & 1) ? s0 : s1;
      const float4* src4 = (const float4*)(scur + (size_t)b * SDIM);
      float4* sm4 = (float4*)sm;
      for (int g = tid; g < SDIM / 4; g += 256) sm4[g] = src4[g];
      __syncthreads();
      // u[d] = Ex.x + Eh.h + Em.m   (32 lanes per d)
      int d = tid >> 5, l = tid & 31;
      const float* xrow = x + ((size_t)b * SEQ + t) * IN_D;
      float acc = 0.f;
      for (int it = 0; it < 16; ++it) { int k = l + 32 * it; acc += Ex[(size_t)d * IN_D + k] * xrow[k]; }
      for (int it = 0; it < 32; ++it) { int k = l + 32 * it; acc += Eh[(size_t)d * HID + k] * sm[k]; }
      for (int it = 0; it < 64; ++it) { int k = l + 32 * it; acc += Em[(size_t)d * MFLAT + k] * sm[HID + k]; }
      for (int off = 16; off; off >>= 1) acc += __shfl_xor(acc, off);
      if (l == 0) ush[d] = acc;
      __syncthreads();
      // m'[d][p] = sum_o A[p][o] m[d][o] + Bd[p]*u[d]
      int p0 = l * 8;
      float u = ush[d];
      const float4* bd4 = (const float4*)(Bd + p0);
      float4 b0q = bd4[0], b1q = bd4[1];
      float a0 = b0q.x * u, a1 = b0q.y * u, a2 = b0q.z * u, a3 = b0q.w * u;
      float a4 = b1q.x * u, a5 = b1q.y * u, a6 = b1q.z * u, a7 = b1q.w * u;
      const float* mrow = sm + HID + d * ORD;
      #pragma unroll 4
      for (int o = 0; o < ORD; ++o) {
        float mv = mrow[o];
        const float4* aq = (const float4*)(AdT + (size_t)o * ORD + p0);
        float4 q0 = aq[0], q1 = aq[1];
        a0 = fmaf(q0.x, mv, a0); a1 = fmaf(q0.y, mv, a1);
        a2 = fmaf(q0.z, mv, a2); a3 = fmaf(q0.w, mv, a3);
        a4 = fmaf(q1.x, mv, a4); a5 = fmaf(q1.y, mv, a5);
        a6 = fmaf(q1.z, mv, a6); a7 = fmaf(q1.w, mv, a7);
      }
      float4* mo4 = (float4*)(snxt + (size_t)b * SDIM + HID + d * ORD + p0);
      mo4[0] = make_float4(a0, a1, a2, a3);
      mo4[1] = make_float4(a4, a5, a6, a7);
      grid_barrier(cnt, (unsigned)(t + 1) * NBLK);
    }
  } else {
    // ================= H role =================
    int hid_ = blockIdx.x - 64;
    int bt = hid_ >> 6, itl = hid_ & 63;
    int b0 = bt * 16, i0 = itl * 16;
    int w = tid >> 6, lane = tid & 63;
    int pos_b = w >> 1, pos_i = w & 1;

    for (int t = 0; t < SEQ; ++t) {
      const float* scur = (t & 1) ? s1 : s0;
      float* snxt = (t & 1) ? s0 : s1;
      float acc[64];
      #pragma unroll
      for (int j = 0; j < 64; ++j) acc[j] = 0.f;

      for (int c = 0; c < NCH; ++c) {
        __syncthreads();
        int k0 = c * 256;
        #pragma unroll
        for (int r = 0; r < 8; ++r) {
          int row = r * 4 + w;     // 0..31
          const float4* g4;
          if (row < 16) {
            int bb = b0 + row;
            if (k0 < IN_D) g4 = (const float4*)(x + ((size_t)bb * SEQ + t) * IN_D + k0) + lane;
            else           g4 = (const float4*)(scur + (size_t)bb * SDIM + (k0 - IN_D)) + lane;
          } else {
            int ii = i0 + row - 16;
            g4 = (const float4*)(Gcat + (size_t)ii * KTOT + k0) + lane;
          }
          ((float4*)sm)[r * 256 + tid] = *g4;
        }
        __syncthreads();
        const float4* sb = (const float4*)sm;
        float4 sf[8], gf[8];
        #pragma unroll
        for (int j = 0; j < 8; ++j) {
          sf[j] = sb[(pos_b * 8 + j) * 64 + lane];
          gf[j] = sb[(16 + pos_i * 8 + j) * 64 + lane];
        }
        #pragma unroll
        for (int mb = 0; mb < 8; ++mb) {
          #pragma unroll
          for (int mi = 0; mi < 8; ++mi) {
            acc[mb * 8 + mi] += sf[mb].x * gf[mi].x + sf[mb].y * gf[mi].y
                              + sf[mb].z * gf[mi].z + sf[mb].w * gf[mi].w;
          }
        }
      }
      // reduce 64 k-slots
      __syncthreads();
      {
        float4* red4 = (float4*)sm;
        #pragma unroll
        for (int j4 = 0; j4 < 16; ++j4) {
          int j = j4 * 4;
          red4[(lane * 4 + w) * 16 + j4] = make_float4(acc[j], acc[j + 1], acc[j + 2], acc[j + 3]);
        }
      }
      __syncthreads();
      int bl = tid >> 4, il = tid & 15;
      int p = ((bl >> 3) << 1) | (il >> 3);
      int j = (bl & 7) * 8 + (il & 7);
      float v = 0.f;
      for (int s = 0; s < 64; ++s) v += sm[s * 256 + p * 64 + j];
      float hv = tanhf(v);
      int bb = b0 + bl, ii = i0 + il;
      snxt[(size_t)bb * SDIM + ii] = hv;
      out[((size_t)bb * SEQ + t) * HID + ii] = hv;
      grid_barrier(cnt, (unsigned)(t + 1) * NBLK);
    }
  }
}

// ---------------- launch ----------------
extern "C" void kernel_launch(void* const* d_in, const int* in_sizes, int n_in,
                              void* d_out, int out_size, void* d_ws, size_t ws_size,
                              hipStream_t stream) {
  const float* x  = (const float*)d_in[0];
  const float* Ex = (const float*)d_in[1];
  const float* Eh = (const float*)d_in[2];
  const float* Em = (const float*)d_in[3];
  const float* Wx = (const float*)d_in[4];
  const float* Wh = (const float*)d_in[5];
  const float* Wm = (const float*)d_in[6];
  float* out = (float*)d_out;
  float* ws = (float*)d_ws;

  float* dAnat = ws;                        // 65536
  float* dAdT  = dAnat + 65536;             // 65536
  float* dBd   = dAdT + 65536;              // 256 (+256 pad)
  float* dWmB  = dBd + 512;                 // 8192
  float* dGcat = dWmB + 8192;               // 1024*3584
  float* scat0 = dGcat + (size_t)HID * KTOT;
  float* scat1 = scat0 + (size_t)B_SZ * SDIM;
  unsigned* dCnt = (unsigned*)(scat1 + (size_t)B_SZ * SDIM);

  static float h_AdT[ORD * ORD];
  static float h_Anat[ORD * ORD];
  static float h_Bd[ORD];
  compute_AB_host(h_AdT, h_Anat, h_Bd);
  hipMemcpyAsync(dAdT,  h_AdT,  sizeof(h_AdT),  hipMemcpyHostToDevice, stream);
  hipMemcpyAsync(dAnat, h_Anat, sizeof(h_Anat), hipMemcpyHostToDevice, stream);
  hipMemcpyAsync(dBd,   h_Bd,   sizeof(h_Bd),   hipMemcpyHostToDevice, stream);

  hipMemsetAsync(scat0, 0, (size_t)B_SZ * SDIM * sizeof(float), stream);
  hipMemsetAsync(dCnt, 0, sizeof(unsigned), stream);

  k_wmb<<<dim3(HID), dim3(256), 0, stream>>>(Wm, dBd, dWmB);
  k_gcat<<<dim3(HID), dim3(256), 0, stream>>>(Wx, Wh, Wm, Ex, Eh, Em, dAnat, dWmB, dGcat);

  k_persist<<<dim3(NBLK), dim3(256), 0, stream>>>(
      x, Ex, Eh, Em, dGcat, dAdT, dBd, scat0, scat1, out, dCnt);
}

// Round 5
// 21121.532 us; speedup vs baseline: 2.5731x; 1.3861x over previous
//
#include <hip/hip_runtime.h>
#include <cmath>
#include <vector>

#define B_SZ 64
#define SEQ 512
#define IN_D 512
#define HID 1024
#define MEM_DIM 8
#define ORD 256
#define MFLAT 2048
#define KTOT 3584            // x(512) | h(1024) | m(2048)
#define NH 128               // H-role blocks
#define NM 64                // M-role blocks
#define NBLK (NH + NM)       // 192

typedef __attribute__((ext_vector_type(8))) short short8v;
typedef __attribute__((ext_vector_type(4))) float f32x4;

// RNE float->bf16
__device__ __host__ inline unsigned short f2bf(float f) {
  union { float f; unsigned u; } v; v.f = f;
  unsigned r = v.u + 0x7FFF + ((v.u >> 16) & 1);
  return (unsigned short)(r >> 16);
}
__device__ __host__ inline float bf2f(unsigned short h) {
  union { unsigned u; float f; } v; v.u = ((unsigned)h) << 16;
  return v.f;
}

// ---------------- host-side expm (double, scaling & squaring) ----------------
static void matmul_d(const double* A, const double* B, double* C, int n) {
  for (int i = 0; i < n; ++i) {
    double* Ci = C + (size_t)i * n;
    for (int j = 0; j < n; ++j) Ci[j] = 0.0;
    const double* Ai = A + (size_t)i * n;
    for (int k = 0; k < n; ++k) {
      double a = Ai[k];
      const double* Bk = B + (size_t)k * n;
      for (int j = 0; j < n; ++j) Ci[j] += a * Bk[j];
    }
  }
}

static void compute_AB_host(float* AdT, float* Anat, float* Bd) {
  const int q = ORD, n = ORD + 1;
  const double theta = 512.0;
  std::vector<double> M((size_t)n * n, 0.0);
  for (int i = 0; i < q; ++i) {
    double r = (2.0 * i + 1.0) / theta;
    for (int j = 0; j < q; ++j) {
      double v = (i < j) ? -1.0 : ((((i - j) % 2) == 1) ? 1.0 : -1.0);
      M[(size_t)i * n + j] = v * r;
    }
    M[(size_t)i * n + q] = (((i % 2) == 0) ? 1.0 : -1.0) * r;
  }
  double norm = 0.0;
  for (int j = 0; j < n; ++j) {
    double s = 0.0;
    for (int i = 0; i < n; ++i) s += fabs(M[(size_t)i * n + j]);
    if (s > norm) norm = s;
  }
  int s = 0;
  while (norm > 0.25) { norm *= 0.5; ++s; }
  double sc = ldexp(1.0, -s);
  for (size_t i = 0; i < M.size(); ++i) M[i] *= sc;
  std::vector<double> E((size_t)n * n, 0.0), P = M, T((size_t)n * n);
  for (int i = 0; i < n; ++i) E[(size_t)i * n + i] = 1.0;
  for (size_t i = 0; i < M.size(); ++i) E[i] += M[i];
  for (int k = 2; k <= 30; ++k) {
    matmul_d(P.data(), M.data(), T.data(), n);
    double inv = 1.0 / (double)k, mx = 0.0;
    for (size_t i = 0; i < T.size(); ++i) {
      T[i] *= inv;
      double a = fabs(T[i]);
      if (a > mx) mx = a;
    }
    P.swap(T);
    for (size_t i = 0; i < M.size(); ++i) E[i] += P[i];
    if (mx < 1e-19) break;
  }
  for (int it = 0; it < s; ++it) {
    matmul_d(E.data(), E.data(), T.data(), n);
    E.swap(T);
  }
  for (int p = 0; p < q; ++p) {
    for (int o = 0; o < q; ++o) {
      float v = (float)E[(size_t)p * n + o];
      AdT[(size_t)o * q + p] = v;
      Anat[(size_t)p * q + o] = v;
    }
    Bd[p] = (float)E[(size_t)p * n + q];
  }
}

// ---------------- precompute: WmB[i][d] = sum_p Wm[i][d*256+p] * Bd[p] ----------------
__global__ __launch_bounds__(256) void k_wmb(const float* __restrict__ Wm,
                                             const float* __restrict__ Bd,
                                             float* __restrict__ WmB) {
  int i = blockIdx.x;
  int d = threadIdx.x >> 5, l = threadIdx.x & 31;
  const float* wr = Wm + (size_t)i * MFLAT + d * ORD;
  float acc = 0.f;
  #pragma unroll
  for (int j = 0; j < 8; ++j) { int p = l + 32 * j; acc += wr[p] * Bd[p]; }
  for (int off = 16; off; off >>= 1) acc += __shfl_xor(acc, off);
  if (l == 0) WmB[i * 8 + d] = acc;
}

// ---------------- precompute: Ghi/Glo = split-bf16([Gx | Gh' | Gm']) ----------------
__global__ __launch_bounds__(256) void k_gcat(
    const float* __restrict__ Wx, const float* __restrict__ Wh,
    const float* __restrict__ Wm, const float* __restrict__ Ex,
    const float* __restrict__ Eh, const float* __restrict__ Em,
    const float* __restrict__ Anat, const float* __restrict__ WmB,
    unsigned short* __restrict__ Ghi, unsigned short* __restrict__ Glo) {
  __shared__ float wm[MFLAT];
  __shared__ float wb[8];
  int i = blockIdx.x, tid = threadIdx.x;
  for (int k = tid; k < MFLAT; k += 256) wm[k] = Wm[(size_t)i * MFLAT + k];
  if (tid < 8) wb[tid] = WmB[i * 8 + tid];
  __syncthreads();
  unsigned short* grh = Ghi + (size_t)i * KTOT;
  unsigned short* grl = Glo + (size_t)i * KTOT;
  for (int c = tid; c < KTOT; c += 256) {
    float v;
    if (c < IN_D) {
      v = Wx[(size_t)i * IN_D + c];
      #pragma unroll
      for (int d = 0; d < 8; ++d) v += wb[d] * Ex[(size_t)d * IN_D + c];
    } else if (c < IN_D + HID) {
      int j = c - IN_D;
      v = Wh[(size_t)i * HID + j];
      #pragma unroll
      for (int d = 0; d < 8; ++d) v += wb[d] * Eh[(size_t)d * HID + j];
    } else {
      int cm = c - IN_D - HID;        // (d,o)
      int dd = cm >> 8, o = cm & 255;
      v = 0.f;
      const float* wmd = wm + dd * ORD;
      for (int p = 0; p < ORD; ++p) v += wmd[p] * Anat[(size_t)p * ORD + o];
      #pragma unroll
      for (int d = 0; d < 8; ++d) v += wb[d] * Em[(size_t)d * MFLAT + cm];
    }
    unsigned short hi = f2bf(v);
    grh[c] = hi;
    grl[c] = f2bf(v - bf2f(hi));
  }
}

// ---------------- device-scope grid barrier ----------------
__device__ inline void grid_barrier(unsigned* cnt, unsigned target) {
  __syncthreads();   // all waves' stores drained (vmcnt(0) before s_barrier)
  if (threadIdx.x == 0) {
    __hip_atomic_fetch_add(cnt, 1u, __ATOMIC_RELEASE, __HIP_MEMORY_SCOPE_AGENT);
    while (__hip_atomic_load(cnt, __ATOMIC_RELAXED, __HIP_MEMORY_SCOPE_AGENT) < target)
      __builtin_amdgcn_s_sleep(1);
    __builtin_amdgcn_fence(__ATOMIC_ACQUIRE, "agent");
  }
  __syncthreads();
}

// ---------------- persistent kernel ----------------
// blocks [0,128): H role, 4 waves = 2 tile-waves x 2 K-halves; tile 32b x 16i.
// blocks [128,192): M role, batch b: u-dot + m' = A m + Bd u (fp32) + hi/lo mirrors.
__global__ __launch_bounds__(256) void k_persist(
    const float* __restrict__ x, const float* __restrict__ Ex,
    const float* __restrict__ Eh, const float* __restrict__ Em,
    const unsigned short* __restrict__ Ghi, const unsigned short* __restrict__ Glo,
    const float* __restrict__ AdT, const float* __restrict__ Bd,
    unsigned short* __restrict__ sh0, unsigned short* __restrict__ sh1,
    unsigned short* __restrict__ sl0, unsigned short* __restrict__ sl1,
    float* __restrict__ hfp0, float* __restrict__ hfp1,
    float* __restrict__ mfp0, float* __restrict__ mfp1,
    float* __restrict__ out, unsigned* __restrict__ cnt) {
  int tid = threadIdx.x;
  unsigned ep = 0;

  if (blockIdx.x < NH) {
    // ================= H role =================
    __shared__ float hx[2][64][4];
    int it = blockIdx.x & 63, bh = blockIdx.x >> 6;
    int w = tid >> 6, lane = tid & 63;
    int tw = w & 1, kh = w >> 1;
    int b0 = bh * 32 + tw * 16;
    int i0 = it * 16;
    size_t aoff = (size_t)(b0 + (lane & 15)) * KTOT + (lane >> 4) * 8;
    const unsigned short* bh_ = Ghi + (size_t)(i0 + (lane & 15)) * KTOT + (lane >> 4) * 8;
    const unsigned short* bl_ = Glo + (size_t)(i0 + (lane & 15)) * KTOT + (lane >> 4) * 8;

    grid_barrier(cnt, (++ep) * NBLK);          // wait x_0 seed

    for (int t = 0; t < SEQ; ++t) {
      const unsigned short* ah_ = ((t & 1) ? sh1 : sh0) + aoff;
      const unsigned short* al_ = ((t & 1) ? sl1 : sl0) + aoff;
      unsigned short* snh = (t & 1) ? sh0 : sh1;
      unsigned short* snl = (t & 1) ? sl0 : sl1;
      float* hn = (t & 1) ? hfp0 : hfp1;

      f32x4 ahh = {0.f,0.f,0.f,0.f}, alh = {0.f,0.f,0.f,0.f}, ahl = {0.f,0.f,0.f,0.f};
      int kbase = kh * 1792;
      #pragma unroll 4
      for (int kk = 0; kk < 56; ++kk) {
        int k = kbase + kk * 32;
        short8v avh = *(const short8v*)(ah_ + k);
        short8v avl = *(const short8v*)(al_ + k);
        short8v bvh = *(const short8v*)(bh_ + k);
        short8v bvl = *(const short8v*)(bl_ + k);
        ahh = __builtin_amdgcn_mfma_f32_16x16x32_bf16(avh, bvh, ahh, 0, 0, 0);
        alh = __builtin_amdgcn_mfma_f32_16x16x32_bf16(avl, bvh, alh, 0, 0, 0);
        ahl = __builtin_amdgcn_mfma_f32_16x16x32_bf16(avh, bvl, ahl, 0, 0, 0);
      }
      f32x4 acc = ahh + alh + ahl;
      if (kh == 1) {
        *(f32x4*)&hx[tw][lane][0] = acc;
      }
      __syncthreads();
      if (kh == 0) {
        f32x4 o4 = *(const f32x4*)&hx[tw][lane][0];
        #pragma unroll
        for (int r = 0; r < 4; ++r) {
          float v = acc[r] + o4[r];
          float hv = tanhf(v);
          int b = b0 + (lane >> 4) * 4 + r;
          int i = i0 + (lane & 15);
          hn[(size_t)b * HID + i] = hv;
          unsigned short hi = f2bf(hv);
          snh[(size_t)b * KTOT + IN_D + i] = hi;
          snl[(size_t)b * KTOT + IN_D + i] = f2bf(hv - bf2f(hi));
          __builtin_nontemporal_store(hv, &out[((size_t)b * SEQ + t) * HID + i]);
        }
      }
      grid_barrier(cnt, (++ep) * NBLK);
    }
  } else {
    // ================= M role =================
    __shared__ float sst[KTOT];        // [x_t | h | m] fp32, 14 KiB
    int b = blockIdx.x - NH;
    int d = tid >> 5, l = tid & 31;
    int p0 = l * 8;
    const float* exr = Ex + (size_t)d * IN_D;
    const float* ehr = Eh + (size_t)d * HID;
    const float* emr = Em + (size_t)d * MFLAT;
    float bdv[8];
    #pragma unroll
    for (int j = 0; j < 8; ++j) bdv[j] = Bd[p0 + j];

    // seed x_0 hi/lo
    {
      const float* xr = x + (size_t)b * SEQ * IN_D;
      for (int k = tid; k < IN_D; k += 256) {
        float xv = xr[k];
        unsigned short hi = f2bf(xv);
        sh0[(size_t)b * KTOT + k] = hi;
        sl0[(size_t)b * KTOT + k] = f2bf(xv - bf2f(hi));
      }
    }
    grid_barrier(cnt, (++ep) * NBLK);

    for (int t = 0; t < SEQ; ++t) {
      const float* hc = (t & 1) ? hfp1 : hfp0;
      const float* mc = (t & 1) ? mfp1 : mfp0;
      float* mn = (t & 1) ? mfp0 : mfp1;
      unsigned short* snh = (t & 1) ? sh0 : sh1;
      unsigned short* snl = (t & 1) ? sl0 : sl1;

      // stage [x_t | h | m] fp32 to LDS
      const float* xrow = x + ((size_t)b * SEQ + t) * IN_D;
      #pragma unroll
      for (int j = 0; j < 14; ++j) {
        int k = tid + 256 * j;
        float v;
        if (k < IN_D) v = xrow[k];
        else if (k < IN_D + HID) v = hc[(size_t)b * HID + (k - IN_D)];
        else v = mc[(size_t)b * MFLAT + (k - IN_D - HID)];
        sst[k] = v;
      }
      __syncthreads();

      // u[d] = Ex.x + Eh.h + Em.m  (32 lanes per d)
      float ua = 0.f;
      #pragma unroll 4
      for (int j = 0; j < 16; ++j) { int k = l + 32 * j; ua += exr[k] * sst[k]; }
      #pragma unroll 4
      for (int j = 0; j < 32; ++j) { int k = l + 32 * j; ua += ehr[k] * sst[IN_D + k]; }
      #pragma unroll 4
      for (int j = 0; j < 64; ++j) { int k = l + 32 * j; ua += emr[k] * sst[IN_D + HID + k]; }
      #pragma unroll
      for (int off = 16; off; off >>= 1) ua += __shfl_xor(ua, off);

      // m'[d][p0..p0+7] = sum_o AdT[o][p] m[d][o] + Bd[p] u
      float a0 = bdv[0]*ua, a1 = bdv[1]*ua, a2 = bdv[2]*ua, a3 = bdv[3]*ua;
      float a4 = bdv[4]*ua, a5 = bdv[5]*ua, a6 = bdv[6]*ua, a7 = bdv[7]*ua;
      const float* mrow = sst + IN_D + HID + d * ORD;
      #pragma unroll 4
      for (int o = 0; o < ORD; ++o) {
        float mv = mrow[o];
        const float4* aq = (const float4*)(AdT + (size_t)o * ORD + p0);
        float4 q0 = aq[0], q1 = aq[1];
        a0 = fmaf(q0.x, mv, a0); a1 = fmaf(q0.y, mv, a1);
        a2 = fmaf(q0.z, mv, a2); a3 = fmaf(q0.w, mv, a3);
        a4 = fmaf(q1.x, mv, a4); a5 = fmaf(q1.y, mv, a5);
        a6 = fmaf(q1.z, mv, a6); a7 = fmaf(q1.w, mv, a7);
      }
      float4* mo4 = (float4*)(mn + (size_t)b * MFLAT + d * ORD + p0);
      mo4[0] = make_float4(a0, a1, a2, a3);
      mo4[1] = make_float4(a4, a5, a6, a7);
      // hi/lo bf16 mirrors
      float av[8] = { a0, a1, a2, a3, a4, a5, a6, a7 };
      unsigned short ph[8], pl[8];
      #pragma unroll
      for (int j = 0; j < 8; ++j) {
        ph[j] = f2bf(av[j]);
        pl[j] = f2bf(av[j] - bf2f(ph[j]));
      }
      size_t moff = (size_t)b * KTOT + IN_D + HID + d * ORD + p0;
      *(short8v*)(snh + moff) = *(short8v*)ph;
      *(short8v*)(snl + moff) = *(short8v*)pl;

      // seed x_{t+1} hi/lo
      if (t + 1 < SEQ) {
        const float* xn = x + ((size_t)b * SEQ + t + 1) * IN_D;
        for (int k = tid; k < IN_D; k += 256) {
          float xv = xn[k];
          unsigned short hi = f2bf(xv);
          snh[(size_t)b * KTOT + k] = hi;
          snl[(size_t)b * KTOT + k] = f2bf(xv - bf2f(hi));
        }
      }
      __syncthreads();   // sst reads done before next-step overwrite
      grid_barrier(cnt, (++ep) * NBLK);
    }
  }
}

// ---------------- launch ----------------
extern "C" void kernel_launch(void* const* d_in, const int* in_sizes, int n_in,
                              void* d_out, int out_size, void* d_ws, size_t ws_size,
                              hipStream_t stream) {
  const float* x  = (const float*)d_in[0];
  const float* Ex = (const float*)d_in[1];
  const float* Eh = (const float*)d_in[2];
  const float* Em = (const float*)d_in[3];
  const float* Wx = (const float*)d_in[4];
  const float* Wh = (const float*)d_in[5];
  const float* Wm = (const float*)d_in[6];
  float* out = (float*)d_out;
  float* ws = (float*)d_ws;

  float* dAnat = ws;                         // 65536 f
  float* dAdT  = dAnat + 65536;              // 65536 f
  float* dBd   = dAdT + 65536;               // 512 f
  float* dWmB  = dBd + 512;                  // 8192 f
  unsigned short* dGhi = (unsigned short*)(dWmB + 8192);      // 1024*3584 ush
  unsigned short* dGlo = dGhi + (size_t)HID * KTOT;
  unsigned short* sh0  = dGlo + (size_t)HID * KTOT;           // 64*3584 ush each
  unsigned short* sh1  = sh0 + (size_t)B_SZ * KTOT;
  unsigned short* sl0  = sh1 + (size_t)B_SZ * KTOT;
  unsigned short* sl1  = sl0 + (size_t)B_SZ * KTOT;
  float* hfp0 = (float*)(sl1 + (size_t)B_SZ * KTOT);
  float* hfp1 = hfp0 + B_SZ * HID;
  float* mfp0 = hfp1 + B_SZ * HID;
  float* mfp1 = mfp0 + B_SZ * MFLAT;
  unsigned* dCnt = (unsigned*)(mfp1 + B_SZ * MFLAT);

  static float h_AdT[ORD * ORD];
  static float h_Anat[ORD * ORD];
  static float h_Bd[ORD];
  compute_AB_host(h_AdT, h_Anat, h_Bd);
  hipMemcpyAsync(dAdT,  h_AdT,  sizeof(h_AdT),  hipMemcpyHostToDevice, stream);
  hipMemcpyAsync(dAnat, h_Anat, sizeof(h_Anat), hipMemcpyHostToDevice, stream);
  hipMemcpyAsync(dBd,   h_Bd,   sizeof(h_Bd),   hipMemcpyHostToDevice, stream);

  hipMemsetAsync(sh0, 0, (size_t)B_SZ * KTOT * sizeof(unsigned short), stream);
  hipMemsetAsync(sl0, 0, (size_t)B_SZ * KTOT * sizeof(unsigned short), stream);
  hipMemsetAsync(hfp0, 0, (size_t)B_SZ * HID * sizeof(float), stream);
  hipMemsetAsync(mfp0, 0, (size_t)B_SZ * MFLAT * sizeof(float), stream);
  hipMemsetAsync(dCnt, 0, sizeof(unsigned), stream);

  k_wmb<<<dim3(HID), dim3(256), 0, stream>>>(Wm, dBd, dWmB);
  k_gcat<<<dim3(HID), dim3(256), 0, stream>>>(Wx, Wh, Wm, Ex, Eh, Em, dAnat, dWmB, dGhi, dGlo);

  k_persist<<<dim3(NBLK), dim3(256), 0, stream>>>(
      x, Ex, Eh, Em, dGhi, dGlo, dAdT, dBd, sh0, sh1, sl0, sl1,
      hfp0, hfp1, mfp0, mfp1, out, dCnt);
}

// Round 6
// 19407.292 us; speedup vs baseline: 2.8004x; 1.0883x over previous
//
#include <hip/hip_runtime.h>
#include <cmath>
#include <vector>

#define B_SZ 64
#define SEQ 512
#define IN_D 512
#define HID 1024
#define MEM_DIM 8
#define ORD 256
#define MFLAT 2048
#define KTOT 3584            // x(512) | h(1024) | m(2048)
#define NH 128               // H-role blocks
#define NM 64                // M-role blocks
#define NBLK (NH + NM)       // 192
#define BAR_STRIDE 16        // u32 stride per block slot (64B)

typedef __attribute__((ext_vector_type(8))) short short8v;
typedef __attribute__((ext_vector_type(4))) float f32x4;

// RNE float->bf16
__device__ __host__ inline unsigned short f2bf(float f) {
  union { float f; unsigned u; } v; v.f = f;
  unsigned r = v.u + 0x7FFF + ((v.u >> 16) & 1);
  return (unsigned short)(r >> 16);
}
__device__ __host__ inline float bf2f(unsigned short h) {
  union { unsigned u; float f; } v; v.u = ((unsigned)h) << 16;
  return v.f;
}

// ---------------- host-side expm (double, scaling & squaring) ----------------
static void matmul_d(const double* A, const double* B, double* C, int n) {
  for (int i = 0; i < n; ++i) {
    double* Ci = C + (size_t)i * n;
    for (int j = 0; j < n; ++j) Ci[j] = 0.0;
    const double* Ai = A + (size_t)i * n;
    for (int k = 0; k < n; ++k) {
      double a = Ai[k];
      const double* Bk = B + (size_t)k * n;
      for (int j = 0; j < n; ++j) Ci[j] += a * Bk[j];
    }
  }
}

static void compute_AB_host(float* AdT, float* Anat, float* Bd) {
  const int q = ORD, n = ORD + 1;
  const double theta = 512.0;
  std::vector<double> M((size_t)n * n, 0.0);
  for (int i = 0; i < q; ++i) {
    double r = (2.0 * i + 1.0) / theta;
    for (int j = 0; j < q; ++j) {
      double v = (i < j) ? -1.0 : ((((i - j) % 2) == 1) ? 1.0 : -1.0);
      M[(size_t)i * n + j] = v * r;
    }
    M[(size_t)i * n + q] = (((i % 2) == 0) ? 1.0 : -1.0) * r;
  }
  double norm = 0.0;
  for (int j = 0; j < n; ++j) {
    double s = 0.0;
    for (int i = 0; i < n; ++i) s += fabs(M[(size_t)i * n + j]);
    if (s > norm) norm = s;
  }
  int s = 0;
  while (norm > 0.25) { norm *= 0.5; ++s; }
  double sc = ldexp(1.0, -s);
  for (size_t i = 0; i < M.size(); ++i) M[i] *= sc;
  std::vector<double> E((size_t)n * n, 0.0), P = M, T((size_t)n * n);
  for (int i = 0; i < n; ++i) E[(size_t)i * n + i] = 1.0;
  for (size_t i = 0; i < M.size(); ++i) E[i] += M[i];
  for (int k = 2; k <= 30; ++k) {
    matmul_d(P.data(), M.data(), T.data(), n);
    double inv = 1.0 / (double)k, mx = 0.0;
    for (size_t i = 0; i < T.size(); ++i) {
      T[i] *= inv;
      double a = fabs(T[i]);
      if (a > mx) mx = a;
    }
    P.swap(T);
    for (size_t i = 0; i < M.size(); ++i) E[i] += P[i];
    if (mx < 1e-19) break;
  }
  for (int it = 0; it < s; ++it) {
    matmul_d(E.data(), E.data(), T.data(), n);
    E.swap(T);
  }
  for (int p = 0; p < q; ++p) {
    for (int o = 0; o < q; ++o) {
      float v = (float)E[(size_t)p * n + o];
      AdT[(size_t)o * q + p] = v;
      Anat[(size_t)p * q + o] = v;
    }
    Bd[p] = (float)E[(size_t)p * n + q];
  }
}

// ---------------- precompute: WmB[i][d] = sum_p Wm[i][d*256+p] * Bd[p] ----------------
__global__ __launch_bounds__(256) void k_wmb(const float* __restrict__ Wm,
                                             const float* __restrict__ Bd,
                                             float* __restrict__ WmB) {
  int i = blockIdx.x;
  int d = threadIdx.x >> 5, l = threadIdx.x & 31;
  const float* wr = Wm + (size_t)i * MFLAT + d * ORD;
  float acc = 0.f;
  #pragma unroll
  for (int j = 0; j < 8; ++j) { int p = l + 32 * j; acc += wr[p] * Bd[p]; }
  for (int off = 16; off; off >>= 1) acc += __shfl_xor(acc, off);
  if (l == 0) WmB[i * 8 + d] = acc;
}

// ---------------- precompute: Ghi/Glo = split-bf16([Gx | Gh' | Gm']) ----------------
__global__ __launch_bounds__(256) void k_gcat(
    const float* __restrict__ Wx, const float* __restrict__ Wh,
    const float* __restrict__ Wm, const float* __restrict__ Ex,
    const float* __restrict__ Eh, const float* __restrict__ Em,
    const float* __restrict__ Anat, const float* __restrict__ WmB,
    unsigned short* __restrict__ Ghi, unsigned short* __restrict__ Glo) {
  __shared__ float wm[MFLAT];
  __shared__ float wb[8];
  int i = blockIdx.x, tid = threadIdx.x;
  for (int k = tid; k < MFLAT; k += 256) wm[k] = Wm[(size_t)i * MFLAT + k];
  if (tid < 8) wb[tid] = WmB[i * 8 + tid];
  __syncthreads();
  unsigned short* grh = Ghi + (size_t)i * KTOT;
  unsigned short* grl = Glo + (size_t)i * KTOT;
  for (int c = tid; c < KTOT; c += 256) {
    float v;
    if (c < IN_D) {
      v = Wx[(size_t)i * IN_D + c];
      #pragma unroll
      for (int d = 0; d < 8; ++d) v += wb[d] * Ex[(size_t)d * IN_D + c];
    } else if (c < IN_D + HID) {
      int j = c - IN_D;
      v = Wh[(size_t)i * HID + j];
      #pragma unroll
      for (int d = 0; d < 8; ++d) v += wb[d] * Eh[(size_t)d * HID + j];
    } else {
      int cm = c - IN_D - HID;        // (d,o)
      int dd = cm >> 8, o = cm & 255;
      v = 0.f;
      const float* wmd = wm + dd * ORD;
      for (int p = 0; p < ORD; ++p) v += wmd[p] * Anat[(size_t)p * ORD + o];
      #pragma unroll
      for (int d = 0; d < 8; ++d) v += wb[d] * Em[(size_t)d * MFLAT + cm];
    }
    unsigned short hi = f2bf(v);
    grh[c] = hi;
    grl[c] = f2bf(v - bf2f(hi));
  }
}

// ---------------- atomic-free device-scope grid barrier ----------------
// arr: per-block epoch slots (stride 64B). go: broadcast epoch word.
// Block 0 = master: scans slots, then publishes go.
__device__ inline void grid_barrier(unsigned* __restrict__ arr,
                                    unsigned* __restrict__ go, unsigned ep) {
  __syncthreads();   // all waves' stores issued & drained before release
  if (blockIdx.x == 0) {
    int tid = threadIdx.x;
    if (tid > 0 && tid < NBLK) {
      while (__hip_atomic_load(&arr[tid * BAR_STRIDE], __ATOMIC_RELAXED,
                               __HIP_MEMORY_SCOPE_AGENT) < ep) {}
    }
    __syncthreads();
    if (tid == 0)
      __hip_atomic_store(go, ep, __ATOMIC_RELEASE, __HIP_MEMORY_SCOPE_AGENT);
  } else {
    if (threadIdx.x == 0) {
      __hip_atomic_store(&arr[blockIdx.x * BAR_STRIDE], ep, __ATOMIC_RELEASE,
                         __HIP_MEMORY_SCOPE_AGENT);
      while (__hip_atomic_load(go, __ATOMIC_RELAXED,
                               __HIP_MEMORY_SCOPE_AGENT) < ep) {}
    }
  }
  if (threadIdx.x == 0)
    __builtin_amdgcn_fence(__ATOMIC_ACQUIRE, "agent");
  __syncthreads();
}

// ---------------- persistent kernel ----------------
// blocks [0,128): H role, 4 waves = 2 tile-waves x 2 K-halves; tile 32b x 16i.
// blocks [128,192): M role, batch b: u-dot + m' = A m + Bd u (fp32) + hi/lo mirrors.
__global__ __launch_bounds__(256) void k_persist(
    const float* __restrict__ x, const float* __restrict__ Ex,
    const float* __restrict__ Eh, const float* __restrict__ Em,
    const unsigned short* __restrict__ Ghi, const unsigned short* __restrict__ Glo,
    const float* __restrict__ AdT, const float* __restrict__ Bd,
    unsigned short* __restrict__ sh0, unsigned short* __restrict__ sh1,
    unsigned short* __restrict__ sl0, unsigned short* __restrict__ sl1,
    float* __restrict__ hfp0, float* __restrict__ hfp1,
    float* __restrict__ mfp0, float* __restrict__ mfp1,
    float* __restrict__ out, unsigned* __restrict__ barArr,
    unsigned* __restrict__ barGo) {
  int tid = threadIdx.x;
  unsigned ep = 0;

  if (blockIdx.x < NH) {
    // ================= H role =================
    __shared__ float hx[2][64][4];
    int it = blockIdx.x & 63, bh = blockIdx.x >> 6;
    int w = tid >> 6, lane = tid & 63;
    int tw = w & 1, kh = w >> 1;
    int b0 = bh * 32 + tw * 16;
    int i0 = it * 16;
    size_t aoff = (size_t)(b0 + (lane & 15)) * KTOT + (lane >> 4) * 8;
    const unsigned short* bh_ = Ghi + (size_t)(i0 + (lane & 15)) * KTOT + (lane >> 4) * 8;
    const unsigned short* bl_ = Glo + (size_t)(i0 + (lane & 15)) * KTOT + (lane >> 4) * 8;

    grid_barrier(barArr, barGo, ++ep);         // wait x_0 seed

    for (int t = 0; t < SEQ; ++t) {
      const unsigned short* ah_ = ((t & 1) ? sh1 : sh0) + aoff;
      const unsigned short* al_ = ((t & 1) ? sl1 : sl0) + aoff;
      unsigned short* snh = (t & 1) ? sh0 : sh1;
      unsigned short* snl = (t & 1) ? sl0 : sl1;
      float* hn = (t & 1) ? hfp0 : hfp1;

      f32x4 ahh = {0.f,0.f,0.f,0.f}, alh = {0.f,0.f,0.f,0.f}, ahl = {0.f,0.f,0.f,0.f};
      int kbase = kh * 1792;
      #pragma unroll 4
      for (int kk = 0; kk < 56; ++kk) {
        int k = kbase + kk * 32;
        short8v avh = *(const short8v*)(ah_ + k);
        short8v avl = *(const short8v*)(al_ + k);
        short8v bvh = *(const short8v*)(bh_ + k);
        short8v bvl = *(const short8v*)(bl_ + k);
        ahh = __builtin_amdgcn_mfma_f32_16x16x32_bf16(avh, bvh, ahh, 0, 0, 0);
        alh = __builtin_amdgcn_mfma_f32_16x16x32_bf16(avl, bvh, alh, 0, 0, 0);
        ahl = __builtin_amdgcn_mfma_f32_16x16x32_bf16(avh, bvl, ahl, 0, 0, 0);
      }
      f32x4 acc = ahh + alh + ahl;
      if (kh == 1) {
        *(f32x4*)&hx[tw][lane][0] = acc;
      }
      __syncthreads();
      if (kh == 0) {
        f32x4 o4 = *(const f32x4*)&hx[tw][lane][0];
        #pragma unroll
        for (int r = 0; r < 4; ++r) {
          float v = acc[r] + o4[r];
          float hv = tanhf(v);
          int b = b0 + (lane >> 4) * 4 + r;
          int i = i0 + (lane & 15);
          hn[(size_t)b * HID + i] = hv;
          unsigned short hi = f2bf(hv);
          snh[(size_t)b * KTOT + IN_D + i] = hi;
          snl[(size_t)b * KTOT + IN_D + i] = f2bf(hv - bf2f(hi));
          __builtin_nontemporal_store(hv, &out[((size_t)b * SEQ + t) * HID + i]);
        }
      }
      grid_barrier(barArr, barGo, ++ep);
    }
  } else {
    // ================= M role =================
    __shared__ float sst[KTOT];          // 14336 B: [x_t | h | m] fp32
    __shared__ float part[4][MFLAT];     // 32768 B: o-strip partials
    __shared__ float ush[8];
    int b = blockIdx.x - NH;
    int du = tid >> 5, lu = tid & 31;    // u-dot mapping
    const float* exr = Ex + (size_t)du * IN_D;
    const float* ehr = Eh + (size_t)du * HID;
    const float* emr = Em + (size_t)du * MFLAT;
    int os = tid >> 6;                   // o-strip (= wave id), o in [os*64, os*64+64)
    int p0 = (tid & 63) * 4;             // 4 p's per thread
    int dp0 = tid * 8;                   // reduction: 8 outputs per thread
    int dr = tid >> 5;                   // = dp0 >> 8
    float bdv[8];
    #pragma unroll
    for (int j = 0; j < 8; ++j) bdv[j] = Bd[(dp0 & 255) + j];

    // seed x_0 hi/lo
    {
      const float* xr = x + (size_t)b * SEQ * IN_D;
      for (int k = tid; k < IN_D; k += 256) {
        float xv = xr[k];
        unsigned short hi = f2bf(xv);
        sh0[(size_t)b * KTOT + k] = hi;
        sl0[(size_t)b * KTOT + k] = f2bf(xv - bf2f(hi));
      }
    }
    grid_barrier(barArr, barGo, ++ep);

    for (int t = 0; t < SEQ; ++t) {
      const float* hc = (t & 1) ? hfp1 : hfp0;
      const float* mc = (t & 1) ? mfp1 : mfp0;
      float* mn = (t & 1) ? mfp0 : mfp1;
      unsigned short* snh = (t & 1) ? sh0 : sh1;
      unsigned short* snl = (t & 1) ? sl0 : sl1;

      // stage [x_t | h | m] fp32 to LDS
      const float* xrow = x + ((size_t)b * SEQ + t) * IN_D;
      #pragma unroll
      for (int j = 0; j < 14; ++j) {
        int k = tid + 256 * j;
        float v;
        if (k < IN_D) v = xrow[k];
        else if (k < IN_D + HID) v = hc[(size_t)b * HID + (k - IN_D)];
        else v = mc[(size_t)b * MFLAT + (k - IN_D - HID)];
        sst[k] = v;
      }
      __syncthreads();

      // u[d] = Ex.x + Eh.h + Em.m  (32 lanes per d)
      float ua = 0.f;
      #pragma unroll 4
      for (int j = 0; j < 16; ++j) { int k = lu + 32 * j; ua += exr[k] * sst[k]; }
      #pragma unroll 4
      for (int j = 0; j < 32; ++j) { int k = lu + 32 * j; ua += ehr[k] * sst[IN_D + k]; }
      #pragma unroll 4
      for (int j = 0; j < 64; ++j) { int k = lu + 32 * j; ua += emr[k] * sst[IN_D + HID + k]; }
      #pragma unroll
      for (int off = 16; off; off >>= 1) ua += __shfl_xor(ua, off);
      if (lu == 0) ush[du] = ua;
      __syncthreads();

      // matvec partials: acc[d][j] += AdT[o][p0+j] * m[d][o], o in this wave's strip.
      // o is wave-uniform per iteration -> m-reads are LDS broadcasts; AdT reads
      // are 1KB contiguous per wave-instr (each AdT element read once per block).
      float acc[8][4];
      #pragma unroll
      for (int d = 0; d < 8; ++d)
        acc[d][0] = acc[d][1] = acc[d][2] = acc[d][3] = 0.f;
      const float* mbase = sst + IN_D + HID;
      #pragma unroll 4
      for (int oo = 0; oo < 64; ++oo) {
        int o = os * 64 + oo;
        float4 q = *(const float4*)(AdT + (size_t)o * ORD + p0);
        #pragma unroll
        for (int d = 0; d < 8; ++d) {
          float mv = mbase[d * ORD + o];
          acc[d][0] = fmaf(q.x, mv, acc[d][0]);
          acc[d][1] = fmaf(q.y, mv, acc[d][1]);
          acc[d][2] = fmaf(q.z, mv, acc[d][2]);
          acc[d][3] = fmaf(q.w, mv, acc[d][3]);
        }
      }
      #pragma unroll
      for (int d = 0; d < 8; ++d)
        *(float4*)&part[os][d * ORD + p0] =
            make_float4(acc[d][0], acc[d][1], acc[d][2], acc[d][3]);
      __syncthreads();

      // reduce strips + Bd*u, store fp32 + hi/lo mirrors (8 contiguous outputs/thread)
      float r[8];
      float uv = ush[dr];
      #pragma unroll
      for (int j = 0; j < 8; ++j) r[j] = bdv[j] * uv;
      #pragma unroll
      for (int s = 0; s < 4; ++s) {
        float4 v0 = *(const float4*)&part[s][dp0];
        float4 v1 = *(const float4*)&part[s][dp0 + 4];
        r[0] += v0.x; r[1] += v0.y; r[2] += v0.z; r[3] += v0.w;
        r[4] += v1.x; r[5] += v1.y; r[6] += v1.z; r[7] += v1.w;
      }
      float4* mo4 = (float4*)(mn + (size_t)b * MFLAT + dp0);
      mo4[0] = make_float4(r[0], r[1], r[2], r[3]);
      mo4[1] = make_float4(r[4], r[5], r[6], r[7]);
      unsigned short ph[8], pl[8];
      #pragma unroll
      for (int j = 0; j < 8; ++j) {
        ph[j] = f2bf(r[j]);
        pl[j] = f2bf(r[j] - bf2f(ph[j]));
      }
      size_t moff = (size_t)b * KTOT + IN_D + HID + dp0;
      *(short8v*)(snh + moff) = *(short8v*)ph;
      *(short8v*)(snl + moff) = *(short8v*)pl;

      // seed x_{t+1} hi/lo
      if (t + 1 < SEQ) {
        const float* xn = x + ((size_t)b * SEQ + t + 1) * IN_D;
        for (int k = tid; k < IN_D; k += 256) {
          float xv = xn[k];
          unsigned short hi = f2bf(xv);
          snh[(size_t)b * KTOT + k] = hi;
          snl[(size_t)b * KTOT + k] = f2bf(xv - bf2f(hi));
        }
      }
      grid_barrier(barArr, barGo, ++ep);
    }
  }
}

// ---------------- launch ----------------
extern "C" void kernel_launch(void* const* d_in, const int* in_sizes, int n_in,
                              void* d_out, int out_size, void* d_ws, size_t ws_size,
                              hipStream_t stream) {
  const float* x  = (const float*)d_in[0];
  const float* Ex = (const float*)d_in[1];
  const float* Eh = (const float*)d_in[2];
  const float* Em = (const float*)d_in[3];
  const float* Wx = (const float*)d_in[4];
  const float* Wh = (const float*)d_in[5];
  const float* Wm = (const float*)d_in[6];
  float* out = (float*)d_out;
  float* ws = (float*)d_ws;

  float* dAnat = ws;                         // 65536 f
  float* dAdT  = dAnat + 65536;              // 65536 f
  float* dBd   = dAdT + 65536;               // 512 f
  float* dWmB  = dBd + 512;                  // 8192 f
  unsigned short* dGhi = (unsigned short*)(dWmB + 8192);      // 1024*3584 ush
  unsigned short* dGlo = dGhi + (size_t)HID * KTOT;
  unsigned short* sh0  = dGlo + (size_t)HID * KTOT;           // 64*3584 ush each
  unsigned short* sh1  = sh0 + (size_t)B_SZ * KTOT;
  unsigned short* sl0  = sh1 + (size_t)B_SZ * KTOT;
  unsigned short* sl1  = sl0 + (size_t)B_SZ * KTOT;
  float* hfp0 = (float*)(sl1 + (size_t)B_SZ * KTOT);
  float* hfp1 = hfp0 + B_SZ * HID;
  float* mfp0 = hfp1 + B_SZ * HID;
  float* mfp1 = mfp0 + B_SZ * MFLAT;
  unsigned* barArr = (unsigned*)(mfp1 + B_SZ * MFLAT);        // NBLK*16 u32
  unsigned* barGo  = barArr + NBLK * BAR_STRIDE;              // 1 u32 (+pad)

  static float h_AdT[ORD * ORD];
  static float h_Anat[ORD * ORD];
  static float h_Bd[ORD];
  compute_AB_host(h_AdT, h_Anat, h_Bd);
  hipMemcpyAsync(dAdT,  h_AdT,  sizeof(h_AdT),  hipMemcpyHostToDevice, stream);
  hipMemcpyAsync(dAnat, h_Anat, sizeof(h_Anat), hipMemcpyHostToDevice, stream);
  hipMemcpyAsync(dBd,   h_Bd,   sizeof(h_Bd),   hipMemcpyHostToDevice, stream);

  hipMemsetAsync(sh0, 0, (size_t)B_SZ * KTOT * sizeof(unsigned short), stream);
  hipMemsetAsync(sl0, 0, (size_t)B_SZ * KTOT * sizeof(unsigned short), stream);
  hipMemsetAsync(hfp0, 0, (size_t)B_SZ * HID * sizeof(float), stream);
  hipMemsetAsync(mfp0, 0, (size_t)B_SZ * MFLAT * sizeof(float), stream);
  hipMemsetAsync(barArr, 0, (NBLK * BAR_STRIDE + 16) * sizeof(unsigned), stream);

  k_wmb<<<dim3(HID), dim3(256), 0, stream>>>(Wm, dBd, dWmB);
  k_gcat<<<dim3(HID), dim3(256), 0, stream>>>(Wx, Wh, Wm, Ex, Eh, Em, dAnat, dWmB, dGhi, dGlo);

  k_persist<<<dim3(NBLK), dim3(256), 0, stream>>>(
      x, Ex, Eh, Em, dGhi, dGlo, dAdT, dBd, sh0, sh1, sl0, sl1,
      hfp0, hfp1, mfp0, mfp1, out, barArr, barGo);
}